// Round 4
// baseline (561.856 us; speedup 1.0000x reference)
//
#include <hip/hip_runtime.h>
#include <stdint.h>

#define GAS __attribute__((address_space(1)))
#define LAS __attribute__((address_space(3)))

typedef __attribute__((ext_vector_type(8))) short short8;
typedef __attribute__((ext_vector_type(4))) float float4v;
typedef __attribute__((ext_vector_type(4))) unsigned int uint4v;

__device__ __forceinline__ unsigned short f2bf(float f) {
  union { float f; unsigned int u; } v; v.f = f;
  unsigned int r = v.u + 0x7fffu + ((v.u >> 16) & 1u);
  return (unsigned short)(r >> 16);
}

__device__ __forceinline__ void async_g2l16(const void* g, void* l) {
  __builtin_amdgcn_global_load_lds((const GAS unsigned int*)g,
                                   (LAS unsigned int*)l, 16, 0, 0);
}

__device__ __forceinline__ void vmem_drain() {
  asm volatile("s_waitcnt vmcnt(0)" ::: "memory");
}

// ---- Kernel A: normalize y -> bf16 fragment-major [t][og][cb][lane][8] ----
// For t=dy*16+dx: fragment (og,cb) is 1KB; lane = q*16 + (o&15), holds
// o = og*16+(o&15), c = cb*32 + q*8 + j  (exactly the 16x16x32 B-operand map).
__global__ void knorm_y(const float* __restrict__ y, unsigned short* __restrict__ y_t2) {
  int o = blockIdx.x;
  int tid = threadIdx.x;
  const float* yo = y + o * 16384;
  float s = 0.f;
  for (int idx = tid; idx < 16384; idx += 256) { float v = yo[idx]; s += v * v; }
  for (int off = 32; off; off >>= 1) s += __shfl_down(s, off, 64);
  __shared__ float red[4];
  if ((tid & 63) == 0) red[tid >> 6] = s;
  __syncthreads();
  float rn = 1.0f / sqrtf(red[0] + red[1] + red[2] + red[3]);
  int og = o >> 4, ol = o & 15;
  for (int idx = tid; idx < 16384; idx += 256) {
    int c = idx >> 8, dy = (idx >> 4) & 15, dx = idx & 15;
    int t = dy * 16 + dx;
    int cb = c >> 5, q = (c >> 3) & 3, j = c & 7;
    size_t dst = (size_t)t * 4096 + (size_t)(og * 2 + cb) * 512 + (q * 16 + ol) * 8 + j;
    y_t2[dst] = f2bf(yo[idx] * rn);
  }
}

// ------- Kernel B: x (NCHW f32) -> x_t bf16 [n][h][w][c] swizzled, + s -----
__global__ void ktrans_x(const float* __restrict__ x, unsigned short* __restrict__ x_t,
                         float* __restrict__ s) {
  int h = blockIdx.x, n = blockIdx.y;
  int tid = threadIdx.x;
  __shared__ __align__(16) unsigned short tb[8192];
  __shared__ float sb[256];
  const float* xb = x + ((size_t)n * 64) * 16384 + h * 128;
  int w = tid & 127, half = tid >> 7;
  float acc = 0.f;
#pragma unroll
  for (int cs = 0; cs < 4; ++cs) {
    short8 tmp;
#pragma unroll
    for (int j = 0; j < 8; ++j) {
      int c = half * 32 + cs * 8 + j;
      float v = xb[(size_t)c * 16384 + w];
      tmp[j] = (short)f2bf(v);
      acc += v * v;
    }
    int chunk = (half * 4 + cs) ^ (w & 7);
    *(short8*)(tb + w * 64 + chunk * 8) = tmp;
  }
  sb[tid] = acc;
  __syncthreads();
  uint4v* dst = (uint4v*)(x_t + ((size_t)(n * 128 + h)) * 8192);
  const uint4v* src = (const uint4v*)tb;
  for (int idx = tid; idx < 1024; idx += 256) dst[idx] = src[idx];
  if (tid < 128) s[((size_t)(n * 128 + h)) * 128 + tid] = sb[tid] + sb[tid + 128];
}

// ---------------- Kernel D: separable 16x16 box sum of s -> 1/sqrt --------
__global__ void knorm_x(const float* __restrict__ s, float* __restrict__ invn) {
  int i = blockIdx.x, n = blockIdx.y;
  int tid = threadIdx.x;  // 128
  __shared__ float colsum[128];
  const float* sp = s + ((size_t)(n * 128 + i)) * 128;
  float a = 0.f;
#pragma unroll
  for (int dy = 0; dy < 16; ++dy) a += sp[dy * 128 + tid];
  colsum[tid] = a;
  __syncthreads();
  if (tid < 113) {
    float acc = 0.f;
#pragma unroll
    for (int dx = 0; dx < 16; ++dx) acc += colsum[tid + dx];
    invn[((size_t)n * 113 + i) * 113 + tid] = 1.0f / sqrtf(acc);
  }
}

// ---------------- Kernel E: main implicit-GEMM conv -----------------------
// R3: LDS pipe was the top pipe (690K cyc/CU vs MFMA 561K): 2x2 wave tiling
// duplicated A reads across the wcol pair. Now 2 waves/block, each wave owns
// a 64(j) x 64(o) tile: A read once per block (-50% LDS traffic), per-block
// B L2 traffic unchanged. Epilogue: direct predicated float4 stores (C/D
// regs 0-3 = 4 consecutive j), no barriers. All fragment layouts unchanged.
__launch_bounds__(128, 2)
__global__ void kconv(const unsigned short* __restrict__ x_t,
                      const unsigned short* __restrict__ y_t2,
                      const float* __restrict__ invn,
                      float* __restrict__ out) {
  int i = blockIdx.x;
  int n = blockIdx.y;
  int tid = threadIdx.x;
  int lane = tid & 63, wave = tid >> 6;  // wave = wrow (j-half)
  int lane15 = lane & 15, q = lane >> 4;

  __shared__ __align__(16) char smem[32768];
  char* const A0 = smem;
  char* const A1 = smem + 16384;

  const char* xrow0 = (const char*)(x_t + ((size_t)(n * 128 + i)) * 8192);

  auto stageA = [&](int dy, char* buf) {
    const char* src = xrow0 + (size_t)dy * 16384;
#pragma unroll
    for (int it = 0; it < 8; ++it) {
      int chunk = it * 128 + wave * 64;  // wave-uniform LDS base
      async_g2l16(src + (chunk + lane) * 16, buf + chunk * 16);
    }
  };

  const short8* ybase = (const short8*)y_t2 + lane;
  auto loadB = [&](int t, short8 bf[4][2]) {
    const short8* p = ybase + (size_t)t * 512;  // 512 short8 per t
#pragma unroll
    for (int nt = 0; nt < 4; ++nt) {
      bf[nt][0] = p[nt * 128];
      bf[nt][1] = p[nt * 128 + 64];
    }
  };

  float4v acc[4][4];
#pragma unroll
  for (int mt = 0; mt < 4; ++mt)
#pragma unroll
    for (int nt = 0; nt < 4; ++nt) acc[mt][nt] = (float4v){0.f, 0.f, 0.f, 0.f};

  int abase[4];
#pragma unroll
  for (int mt = 0; mt < 4; ++mt) abase[mt] = (wave * 64 + mt * 16 + lane15) * 128;

  short8 b0[4][2], b1[4][2];
  stageA(0, A0);
  loadB(0, b0);
  vmem_drain();
  __syncthreads();

#pragma unroll 1
  for (int dy = 0; dy < 16; ++dy) {
    char* Ab = (dy & 1) ? A1 : A0;
    if (dy < 15) {
      __builtin_amdgcn_sched_barrier(0);
      stageA(dy + 1, (dy & 1) ? A0 : A1);
      __builtin_amdgcn_sched_barrier(0);
    }
#pragma unroll
    for (int dx = 0; dx < 16; ++dx) {
      int t = dy * 16 + dx;
      short8(&bc)[4][2] = (dx & 1) ? b1 : b0;
      short8(&bn)[4][2] = (dx & 1) ? b0 : b1;
      if (t < 255) loadB(t + 1, bn);
      int xr = (lane15 + dx) & 7;
#pragma unroll
      for (int cb = 0; cb < 2; ++cb) {
        int aoff = dx * 128 + (((q + cb * 4) ^ xr) << 4);
#pragma unroll
        for (int mt = 0; mt < 4; ++mt) {
          short8 a = *(const short8*)(Ab + abase[mt] + aoff);
#pragma unroll
          for (int nt = 0; nt < 4; ++nt)
            acc[mt][nt] = __builtin_amdgcn_mfma_f32_16x16x32_bf16(a, bc[nt][cb], acc[mt][nt], 0, 0, 0);
        }
      }
    }
    // Drain: all 8 stageA LDS-DMA must land; the 8 newest (dx=15 prefetch
    // loadB for the next dy) may stay in flight across the barrier.
    asm volatile("s_waitcnt vmcnt(8)" ::: "memory");
    __syncthreads();
  }

  // Epilogue: direct stores. C/D map (16x16x32): o = nt*16 + lane15,
  // j = wave*64 + mt*16 + q*4 + reg  -> regs 0..3 are contiguous j.
  const float* ivp = invn + ((size_t)n * 113 + i) * 113;
  float* op = out + (size_t)n * 64 * 12769 + (size_t)i * 113;
  int jbase = wave * 64 + q * 4;
#pragma unroll
  for (int mt = 0; mt < 4; ++mt) {
    int j0 = jbase + mt * 16;
    if (j0 <= 108) {
      float4v iv = *(const float4v*)(ivp + j0);
#pragma unroll
      for (int nt = 0; nt < 4; ++nt) {
        int o = nt * 16 + lane15;
        float4v v = acc[mt][nt];
        float4v r;
        r[0] = fmaxf(v[0] * iv[0], 0.f);
        r[1] = fmaxf(v[1] * iv[1], 0.f);
        r[2] = fmaxf(v[2] * iv[2], 0.f);
        r[3] = fmaxf(v[3] * iv[3], 0.f);
        *(float4v*)(op + (size_t)o * 12769 + j0) = r;
      }
    } else if (j0 == 112) {
      float ivs = ivp[112];
#pragma unroll
      for (int nt = 0; nt < 4; ++nt) {
        int o = nt * 16 + lane15;
        op[(size_t)o * 12769 + 112] = fmaxf(acc[mt][nt][0] * ivs, 0.f);
      }
    }
  }
}

extern "C" void kernel_launch(void* const* d_in, const int* in_sizes, int n_in,
                              void* d_out, int out_size, void* d_ws, size_t ws_size,
                              hipStream_t stream) {
  const float* x = (const float*)d_in[0];
  const float* y = (const float*)d_in[1];
  float* out = (float*)d_out;
  char* ws = (char*)d_ws;
  unsigned short* x_t = (unsigned short*)ws;                 // 33,554,432 B
  unsigned short* y_t2 = (unsigned short*)(ws + 33554432);   //  2,097,152 B
  float* s = (float*)(ws + 35651584);                        //  1,048,576 B
  float* invn = (float*)(ws + 36700160);                     //    817,216 B

  hipLaunchKernelGGL(knorm_y, dim3(64), dim3(256), 0, stream, y, y_t2);
  hipLaunchKernelGGL(ktrans_x, dim3(128, 16), dim3(256), 0, stream, x, x_t, s);
  hipLaunchKernelGGL(knorm_x, dim3(113, 16), dim3(128), 0, stream, s, invn);
  hipLaunchKernelGGL(kconv, dim3(113, 16), dim3(128), 0, stream, x_t, y_t2, invn, out);
}

// Round 5
// 525.593 us; speedup vs baseline: 1.0690x; 1.0690x over previous
//
#include <hip/hip_runtime.h>
#include <stdint.h>

#define GAS __attribute__((address_space(1)))
#define LAS __attribute__((address_space(3)))

typedef __attribute__((ext_vector_type(8))) short short8;
typedef __attribute__((ext_vector_type(4))) float float4v;
typedef __attribute__((ext_vector_type(4))) unsigned int uint4v;

__device__ __forceinline__ unsigned short f2bf(float f) {
  union { float f; unsigned int u; } v; v.f = f;
  unsigned int r = v.u + 0x7fffu + ((v.u >> 16) & 1u);
  return (unsigned short)(r >> 16);
}

__device__ __forceinline__ void async_g2l16(const void* g, void* l) {
  __builtin_amdgcn_global_load_lds((const GAS unsigned int*)g,
                                   (LAS unsigned int*)l, 16, 0, 0);
}

__device__ __forceinline__ void vmem_drain() {
  asm volatile("s_waitcnt vmcnt(0)" ::: "memory");
}

// ---- Kernel A: normalize y -> bf16 fragment-major [t][og][cb][lane][8] ----
// For t=dy*16+dx: fragment (og,cb) is 1KB; lane = q*16 + (o&15), holds
// o = og*16+(o&15), c = cb*32 + q*8 + j  (exactly the 16x16x32 B-operand map).
__global__ void knorm_y(const float* __restrict__ y, unsigned short* __restrict__ y_t2) {
  int o = blockIdx.x;
  int tid = threadIdx.x;
  const float* yo = y + o * 16384;
  float s = 0.f;
  for (int idx = tid; idx < 16384; idx += 256) { float v = yo[idx]; s += v * v; }
  for (int off = 32; off; off >>= 1) s += __shfl_down(s, off, 64);
  __shared__ float red[4];
  if ((tid & 63) == 0) red[tid >> 6] = s;
  __syncthreads();
  float rn = 1.0f / sqrtf(red[0] + red[1] + red[2] + red[3]);
  int og = o >> 4, ol = o & 15;
  for (int idx = tid; idx < 16384; idx += 256) {
    int c = idx >> 8, dy = (idx >> 4) & 15, dx = idx & 15;
    int t = dy * 16 + dx;
    int cb = c >> 5, q = (c >> 3) & 3, j = c & 7;
    size_t dst = (size_t)t * 4096 + (size_t)(og * 2 + cb) * 512 + (q * 16 + ol) * 8 + j;
    y_t2[dst] = f2bf(yo[idx] * rn);
  }
}

// ------- Kernel B: x (NCHW f32) -> x_t bf16 [n][h][w][c] swizzled, + s -----
__global__ void ktrans_x(const float* __restrict__ x, unsigned short* __restrict__ x_t,
                         float* __restrict__ s) {
  int h = blockIdx.x, n = blockIdx.y;
  int tid = threadIdx.x;
  __shared__ __align__(16) unsigned short tb[8192];
  __shared__ float sb[256];
  const float* xb = x + ((size_t)n * 64) * 16384 + h * 128;
  int w = tid & 127, half = tid >> 7;
  float acc = 0.f;
#pragma unroll
  for (int cs = 0; cs < 4; ++cs) {
    short8 tmp;
#pragma unroll
    for (int j = 0; j < 8; ++j) {
      int c = half * 32 + cs * 8 + j;
      float v = xb[(size_t)c * 16384 + w];
      tmp[j] = (short)f2bf(v);
      acc += v * v;
    }
    int chunk = (half * 4 + cs) ^ (w & 7);
    *(short8*)(tb + w * 64 + chunk * 8) = tmp;
  }
  sb[tid] = acc;
  __syncthreads();
  uint4v* dst = (uint4v*)(x_t + ((size_t)(n * 128 + h)) * 8192);
  const uint4v* src = (const uint4v*)tb;
  for (int idx = tid; idx < 1024; idx += 256) dst[idx] = src[idx];
  if (tid < 128) s[((size_t)(n * 128 + h)) * 128 + tid] = sb[tid] + sb[tid + 128];
}

// ---------------- Kernel D: separable 16x16 box sum of s -> 1/sqrt --------
__global__ void knorm_x(const float* __restrict__ s, float* __restrict__ invn) {
  int i = blockIdx.x, n = blockIdx.y;
  int tid = threadIdx.x;  // 128
  __shared__ float colsum[128];
  const float* sp = s + ((size_t)(n * 128 + i)) * 128;
  float a = 0.f;
#pragma unroll
  for (int dy = 0; dy < 16; ++dy) a += sp[dy * 128 + tid];
  colsum[tid] = a;
  __syncthreads();
  if (tid < 113) {
    float acc = 0.f;
#pragma unroll
    for (int dx = 0; dx < 16; ++dx) acc += colsum[tid + dx];
    invn[((size_t)n * 113 + i) * 113 + tid] = 1.0f / sqrtf(acc);
  }
}

// ---------------- Kernel E: main implicit-GEMM conv -----------------------
// R4: REVERT R3's 64x64 tiling (regressed 401->473: MfmaUtil 46%, occupancy
// halved -> B-load latency exposed). Back to 256-thr 2x2 wave tiling.
// NEW: bijective XCD-chunked block swizzle. Grid 1808 = 8 XCDs x 226, and
// 226 = 2 images x 113 rows: each XCD works 2 images -> L2 working set =
// 2MB x_t chunk + 2MB y_t2 = 4MB (fits). FETCH was 272MB (= x_t with zero
// cross-block L2 reuse + y refetch); loadB was HBM-miss (~900cyc) with only
// ~77cyc prefetch cover -> MFMA starved at 60%.
__launch_bounds__(256, 4)
__global__ void kconv(const unsigned short* __restrict__ x_t,
                      const unsigned short* __restrict__ y_t2,
                      const float* __restrict__ invn,
                      float* __restrict__ out) {
  // XCD-chunked swizzle: hw round-robins linear wg id across 8 XCDs.
  int lin = blockIdx.y * 113 + blockIdx.x;
  int wg = (lin & 7) * 226 + (lin >> 3);   // bijective: 1808 = 8*226
  int i = wg % 113;
  int n = wg / 113;
  int tid = threadIdx.x;
  int lane = tid & 63, wave = tid >> 6;
  int lane15 = lane & 15, q = lane >> 4;
  int wrow = wave >> 1, wcol = wave & 1;

  __shared__ __align__(16) char smem[32768];
  char* const A0 = smem;
  char* const A1 = smem + 16384;

  const char* xrow0 = (const char*)(x_t + ((size_t)(n * 128 + i)) * 8192);

  auto stageA = [&](int dy, char* buf) {
    const char* src = xrow0 + (size_t)dy * 16384;
#pragma unroll
    for (int it = 0; it < 4; ++it) {
      int chunk = it * 256 + wave * 64;  // wave-uniform LDS base
      async_g2l16(src + (chunk + lane) * 16, buf + chunk * 16);
    }
  };

  const short8* ybase = (const short8*)(y_t2 + (size_t)wcol * 2048 + (size_t)lane * 8);
  auto loadB = [&](int t, short8 bf[2][2]) {
    const short8* p = ybase + (size_t)t * 512;  // 512 short8 = 4096 shorts per t
    bf[0][0] = p[0];
    bf[0][1] = p[64];
    bf[1][0] = p[128];
    bf[1][1] = p[192];
  };

  float4v acc[4][2];
#pragma unroll
  for (int mt = 0; mt < 4; ++mt)
#pragma unroll
    for (int nt = 0; nt < 2; ++nt) acc[mt][nt] = (float4v){0.f, 0.f, 0.f, 0.f};

  int abase[4];
#pragma unroll
  for (int mt = 0; mt < 4; ++mt) abase[mt] = (wrow * 64 + mt * 16 + lane15) * 128;

  short8 b0[2][2], b1[2][2];
  stageA(0, A0);
  loadB(0, b0);
  vmem_drain();
  __syncthreads();

#pragma unroll 1
  for (int dy = 0; dy < 16; ++dy) {
    char* Ab = (dy & 1) ? A1 : A0;
    if (dy < 15) {
      __builtin_amdgcn_sched_barrier(0);
      stageA(dy + 1, (dy & 1) ? A0 : A1);
      __builtin_amdgcn_sched_barrier(0);
    }
#pragma unroll
    for (int dx = 0; dx < 16; ++dx) {
      int t = dy * 16 + dx;
      // compile-time ping-pong after unroll: no register copies
      short8(&bc)[2][2] = (dx & 1) ? b1 : b0;
      short8(&bn)[2][2] = (dx & 1) ? b0 : b1;
      if (t < 255) loadB(t + 1, bn);
      int xr = (lane15 + dx) & 7;
#pragma unroll
      for (int cb = 0; cb < 2; ++cb) {
        int aoff = dx * 128 + (((q + cb * 4) ^ xr) << 4);
#pragma unroll
        for (int mt = 0; mt < 4; ++mt) {
          short8 a = *(const short8*)(Ab + abase[mt] + aoff);
          acc[mt][0] = __builtin_amdgcn_mfma_f32_16x16x32_bf16(a, bc[0][cb], acc[mt][0], 0, 0, 0);
          acc[mt][1] = __builtin_amdgcn_mfma_f32_16x16x32_bf16(a, bc[1][cb], acc[mt][1], 0, 0, 0);
        }
      }
    }
    // Relaxed drain: all stageA LDS-DMA (pinned oldest by sched_barrier) must
    // land; the 4 newest (dx=15 loadB for next dy) may stay in flight.
    asm volatile("s_waitcnt vmcnt(4)" ::: "memory");
    __syncthreads();
  }

  // Epilogue: two-pass transpose through LDS (o-halves), fuse invn + relu.
  float* cs = (float*)smem;        // 32 x 132 floats = 16896 B
  float* ivs = cs + 4352;          // 128 floats
  const float* ivp = invn + ((size_t)n * 113 + i) * 113;
  if (tid < 128) ivs[tid] = (tid < 113) ? ivp[tid] : 0.f;
  float* op = out + (size_t)n * 64 * 12769 + (size_t)i * 113;
#pragma unroll 1
  for (int p = 0; p < 2; ++p) {
    if (wcol == p) {
#pragma unroll
      for (int mt = 0; mt < 4; ++mt)
#pragma unroll
        for (int nt = 0; nt < 2; ++nt) {
          int row = nt * 16 + lane15;
          int j0 = wrow * 64 + mt * 16 + q * 4;
          *(float4v*)(cs + row * 132 + j0) = acc[mt][nt];
        }
    }
    __syncthreads();
    for (int idx = tid; idx < 4096; idx += 256) {
      int o2 = idx >> 7, j = idx & 127;
      if (j < 113) {
        float v = cs[o2 * 132 + j] * ivs[j];
        op[(size_t)(p * 32 + o2) * 12769 + j] = fmaxf(v, 0.f);
      }
    }
    __syncthreads();
  }
}

extern "C" void kernel_launch(void* const* d_in, const int* in_sizes, int n_in,
                              void* d_out, int out_size, void* d_ws, size_t ws_size,
                              hipStream_t stream) {
  const float* x = (const float*)d_in[0];
  const float* y = (const float*)d_in[1];
  float* out = (float*)d_out;
  char* ws = (char*)d_ws;
  unsigned short* x_t = (unsigned short*)ws;                 // 33,554,432 B
  unsigned short* y_t2 = (unsigned short*)(ws + 33554432);   //  2,097,152 B
  float* s = (float*)(ws + 35651584);                        //  1,048,576 B
  float* invn = (float*)(ws + 36700160);                     //    817,216 B

  hipLaunchKernelGGL(knorm_y, dim3(64), dim3(256), 0, stream, y, y_t2);
  hipLaunchKernelGGL(ktrans_x, dim3(128, 16), dim3(256), 0, stream, x, x_t, s);
  hipLaunchKernelGGL(knorm_x, dim3(113, 16), dim3(128), 0, stream, s, invn);
  hipLaunchKernelGGL(kconv, dim3(113, 16), dim3(256), 0, stream, x_t, y_t2, invn, out);
}